// Round 4
// baseline (451.016 us; speedup 1.0000x reference)
//
#include <hip/hip_runtime.h>
#include <math.h>

namespace {

typedef float f32x4 __attribute__((ext_vector_type(4)));

constexpr int NI   = 8;
constexpr int NC   = 32;
constexpr int NH   = 480;
constexpr int NW   = 480;
constexpr int NPTS = 64 * 64 * 64;          // 262144
constexpr int NOUTC = NC + 5;               // 37
constexpr long long HW = (long long)NH * NW;
constexpr int PPT = 4;                      // points per thread (16B stores)
constexpr int TPB = 256;
constexpr int CG  = 8;                      // channels per gather group
constexpr int NGRP = NC / CG + 1;           // 4 gather groups + 1 extras group

__global__ __launch_bounds__(TPB)
void smear_kernel(const float* __restrict__ coords,   // (3, N)
                  const float* __restrict__ images,   // (I, C, H, W)
                  const float* __restrict__ trans,    // (I, 3, 4)
                  const float* __restrict__ tcw,      // (I, 4, 4)
                  float* __restrict__ out)            // (I, 37, N)
{
#pragma clang fp contract(off)
    const int img = blockIdx.y;
    const int grp = blockIdx.z;

    __shared__ float s_tr[12];   // transformations[img]
    __shared__ float s_t2[4];    // T_cw[img] row 2 (depth row)
    __shared__ float s_cam[3];   // camera center

    const int tid = threadIdx.x;
    if (tid < 12) s_tr[tid] = trans[img * 12 + tid];
    if (tid < 4)  s_t2[tid] = tcw[img * 16 + 8 + tid];
    if (tid < 3) {
        const float* T = tcw + img * 16;
        // cam_center[l] = -(R[0][l]*t[0] + R[1][l]*t[1] + R[2][l]*t[2]), sequential
        float cc = T[0 + tid] * T[3] + T[4 + tid] * T[7];
        cc = cc + T[8 + tid] * T[11];
        s_cam[tid] = -cc;
    }
    __syncthreads();

    const int n0 = (blockIdx.x * TPB + tid) * PPT;
    const f32x4 xv = *(const f32x4*)(coords + n0);
    const f32x4 yv = *(const f32x4*)(coords + NPTS + n0);
    const f32x4 zv = *(const f32x4*)(coords + 2 * NPTS + n0);

    // --- projection: offsets + validity (no divergence downstream) ---
    int   off[4];
    float validity[4];
    #pragma unroll
    for (int k = 0; k < PPT; ++k) {
        const float x = xv[k], y = yv[k], z = zv[k];
        const float p0 = ((s_tr[0] * x + s_tr[1] * y) + s_tr[2]  * z) + s_tr[3];
        const float p1 = ((s_tr[4] * x + s_tr[5] * y) + s_tr[6]  * z) + s_tr[7];
        const float p2 = ((s_tr[8] * x + s_tr[9] * y) + s_tr[10] * z) + s_tr[11];
        const float zsafe = (fabsf(p2) < 1e-8f) ? 1e-8f : p2;
        const float u = p0 / zsafe;
        const float v = p1 / zsafe;
        const bool valid = (p2 > 0.0f) && (u >= 0.0f) && (u <= (float)(NW - 1))
                                       && (v >= 0.0f) && (v <= (float)(NH - 1));
        const int ui = (int)fminf(fmaxf(rintf(u), 0.0f), (float)(NW - 1));
        const int vi = (int)fminf(fmaxf(rintf(v), 0.0f), (float)(NH - 1));
        // invalid lanes all read pixel 0 (one hot line), result multiplied by 0
        off[k]      = valid ? (vi * NW + ui) : 0;
        validity[k] = valid ? 1.0f : 0.0f;
    }

    float* ob = out + (long long)img * NOUTC * NPTS + n0;

    if (grp < NGRP - 1) {
        // --- gather group: CG channels, all loads issued before any store ---
        const int c0 = grp * CG;
        const float* ib = images + ((long long)img * NC + c0) * HW;
        float fv[CG][4];
        #pragma unroll
        for (int c = 0; c < CG; ++c) {
            const float* ip = ib + (long long)c * HW;
            fv[c][0] = ip[off[0]];
            fv[c][1] = ip[off[1]];
            fv[c][2] = ip[off[2]];
            fv[c][3] = ip[off[3]];
        }
        #pragma unroll
        for (int c = 0; c < CG; ++c) {
            f32x4 f;
            f[0] = fv[c][0] * validity[0];
            f[1] = fv[c][1] * validity[1];
            f[2] = fv[c][2] * validity[2];
            f[3] = fv[c][3] * validity[3];
            __builtin_nontemporal_store(f, (f32x4*)(ob + (long long)(c0 + c) * NPTS));
        }
    } else {
        // --- extras group: depth, validity, view-dir ---
        f32x4 d4, a4, x4, y4, z4;
        #pragma unroll
        for (int k = 0; k < PPT; ++k) {
            const float x = xv[k], y = yv[k], z = zv[k];
            d4[k] = ((s_t2[0] * x + s_t2[1] * y) + s_t2[2] * z) + s_t2[3];
            a4[k] = validity[k];
            const float dx = x - s_cam[0];
            const float dy = y - s_cam[1];
            const float dz = z - s_cam[2];
            float nrm = sqrtf((dx * dx + dy * dy) + dz * dz);
            nrm = fmaxf(nrm, 1e-8f);
            x4[k] = dx / nrm;
            y4[k] = dy / nrm;
            z4[k] = dz / nrm;
        }
        __builtin_nontemporal_store(d4, (f32x4*)(ob + (long long)(NC + 0) * NPTS));
        __builtin_nontemporal_store(a4, (f32x4*)(ob + (long long)(NC + 1) * NPTS));
        __builtin_nontemporal_store(x4, (f32x4*)(ob + (long long)(NC + 2) * NPTS));
        __builtin_nontemporal_store(y4, (f32x4*)(ob + (long long)(NC + 3) * NPTS));
        __builtin_nontemporal_store(z4, (f32x4*)(ob + (long long)(NC + 4) * NPTS));
    }
}

} // namespace

extern "C" void kernel_launch(void* const* d_in, const int* in_sizes, int n_in,
                              void* d_out, int out_size, void* d_ws, size_t ws_size,
                              hipStream_t stream)
{
    const float* coords = (const float*)d_in[0];
    const float* images = (const float*)d_in[1];
    const float* trans  = (const float*)d_in[2];
    const float* tcw    = (const float*)d_in[3];
    float* out = (float*)d_out;

    dim3 grid(NPTS / (TPB * PPT), NI, NGRP);
    smear_kernel<<<grid, dim3(TPB), 0, stream>>>(coords, images, trans, tcw, out);
}

// Round 5
// 447.257 us; speedup vs baseline: 1.0084x; 1.0084x over previous
//
#include <hip/hip_runtime.h>
#include <math.h>

namespace {

typedef float f32x4 __attribute__((ext_vector_type(4)));

constexpr int NI   = 8;
constexpr int NC   = 32;
constexpr int NH   = 480;
constexpr int NW   = 480;
constexpr int NPTS = 64 * 64 * 64;          // 262144
constexpr int NOUTC = NC + 5;               // 37
constexpr long long HW = (long long)NH * NW;
constexpr int PPT = 4;                      // points per thread (16B stores)
constexpr int TPB = 256;

__global__ __launch_bounds__(TPB)
void smear_kernel(const float* __restrict__ coords,   // (3, N)
                  const float* __restrict__ images,   // (I, C, H, W)
                  const float* __restrict__ trans,    // (I, 3, 4)
                  const float* __restrict__ tcw,      // (I, 4, 4)
                  float* __restrict__ out)            // (I, 37, N)
{
#pragma clang fp contract(off)
    const int img = blockIdx.y;

    __shared__ float s_tr[12];   // transformations[img]
    __shared__ float s_t2[4];    // T_cw[img] row 2 (depth row)
    __shared__ float s_cam[3];   // camera center

    const int tid = threadIdx.x;
    if (tid < 12) s_tr[tid] = trans[img * 12 + tid];
    if (tid < 4)  s_t2[tid] = tcw[img * 16 + 8 + tid];
    if (tid < 3) {
        const float* T = tcw + img * 16;
        // cam_center[l] = -(R[0][l]*t[0] + R[1][l]*t[1] + R[2][l]*t[2]), sequential
        float cc = T[0 + tid] * T[3] + T[4 + tid] * T[7];
        cc = cc + T[8 + tid] * T[11];
        s_cam[tid] = -cc;
    }
    __syncthreads();

    const int n0 = (blockIdx.x * TPB + tid) * PPT;
    const f32x4 xv = *(const f32x4*)(coords + n0);
    const f32x4 yv = *(const f32x4*)(coords + NPTS + n0);
    const f32x4 zv = *(const f32x4*)(coords + 2 * NPTS + n0);

    // --- projection: offsets + validity (no divergence downstream) ---
    int   off[4];
    float validity[4];
    #pragma unroll
    for (int k = 0; k < PPT; ++k) {
        const float x = xv[k], y = yv[k], z = zv[k];
        const float p0 = ((s_tr[0] * x + s_tr[1] * y) + s_tr[2]  * z) + s_tr[3];
        const float p1 = ((s_tr[4] * x + s_tr[5] * y) + s_tr[6]  * z) + s_tr[7];
        const float p2 = ((s_tr[8] * x + s_tr[9] * y) + s_tr[10] * z) + s_tr[11];
        const float zsafe = (fabsf(p2) < 1e-8f) ? 1e-8f : p2;
        const float u = p0 / zsafe;
        const float v = p1 / zsafe;
        const bool valid = (p2 > 0.0f) && (u >= 0.0f) && (u <= (float)(NW - 1))
                                       && (v >= 0.0f) && (v <= (float)(NH - 1));
        const int ui = (int)fminf(fmaxf(rintf(u), 0.0f), (float)(NW - 1));
        const int vi = (int)fminf(fmaxf(rintf(v), 0.0f), (float)(NH - 1));
        // invalid lanes all read pixel 0 (one hot line), result multiplied by 0
        off[k]      = valid ? (vi * NW + ui) : 0;
        validity[k] = valid ? 1.0f : 0.0f;
    }

    // --- feature gather + full-exec 16B cached stores ---
    const float* ib = images + (long long)img * NC * HW;
    float*       ob = out    + (long long)img * NOUTC * NPTS + n0;
    #pragma unroll
    for (int c = 0; c < NC; ++c) {
        const float* ip = ib + (long long)c * HW;
        f32x4 f;
        f[0] = ip[off[0]] * validity[0];
        f[1] = ip[off[1]] * validity[1];
        f[2] = ip[off[2]] * validity[2];
        f[3] = ip[off[3]] * validity[3];
        *(f32x4*)(ob + (long long)c * NPTS) = f;
    }

    // --- depth, validity, view-dir channels ---
    f32x4 d4, a4, x4, y4, z4;
    #pragma unroll
    for (int k = 0; k < PPT; ++k) {
        const float x = xv[k], y = yv[k], z = zv[k];
        d4[k] = ((s_t2[0] * x + s_t2[1] * y) + s_t2[2] * z) + s_t2[3];
        a4[k] = validity[k];
        const float dx = x - s_cam[0];
        const float dy = y - s_cam[1];
        const float dz = z - s_cam[2];
        float nrm = sqrtf((dx * dx + dy * dy) + dz * dz);
        nrm = fmaxf(nrm, 1e-8f);
        x4[k] = dx / nrm;
        y4[k] = dy / nrm;
        z4[k] = dz / nrm;
    }
    *(f32x4*)(ob + (long long)(NC + 0) * NPTS) = d4;
    *(f32x4*)(ob + (long long)(NC + 1) * NPTS) = a4;
    *(f32x4*)(ob + (long long)(NC + 2) * NPTS) = x4;
    *(f32x4*)(ob + (long long)(NC + 3) * NPTS) = y4;
    *(f32x4*)(ob + (long long)(NC + 4) * NPTS) = z4;
}

} // namespace

extern "C" void kernel_launch(void* const* d_in, const int* in_sizes, int n_in,
                              void* d_out, int out_size, void* d_ws, size_t ws_size,
                              hipStream_t stream)
{
    const float* coords = (const float*)d_in[0];
    const float* images = (const float*)d_in[1];
    const float* trans  = (const float*)d_in[2];
    const float* tcw    = (const float*)d_in[3];
    float* out = (float*)d_out;

    dim3 grid(NPTS / (TPB * PPT), NI);
    smear_kernel<<<grid, dim3(TPB), 0, stream>>>(coords, images, trans, tcw, out);
}